// Round 17
// baseline (168.464 us; speedup 1.0000x reference)
//
#include <hip/hip_runtime.h>
#include <math.h>

#define THREADS 256

typedef float f2v __attribute__((ext_vector_type(2)));
typedef float f4v __attribute__((ext_vector_type(4)));

// ---- codebook: fp32 levels exactly as numpy float32 computes them ----
static constexpr float kLvl[16] = {
    0.0f      / 0.75f, 0.015625f / 0.75f, 0.03125f / 0.75f, 0.046875f / 0.75f,
    0.0625f   / 0.75f, 0.09375f  / 0.75f, 0.125f   / 0.75f, 0.140625f / 0.75f,
    0.1875f   / 0.75f, 0.25f     / 0.75f, 0.28125f / 0.75f, 0.375f    / 0.75f,
    0.5f      / 0.75f, 0.515625f / 0.75f, 0.5625f  / 0.75f, 0.75f     / 0.75f,
};
// exact f64 midpoints of adjacent f32 levels: strict a>mid == numpy f32 argmin (Sterbenz)
static constexpr double kMid[15] = {
    ((double)kLvl[0]  + (double)kLvl[1])  * 0.5, ((double)kLvl[1]  + (double)kLvl[2])  * 0.5,
    ((double)kLvl[2]  + (double)kLvl[3])  * 0.5, ((double)kLvl[3]  + (double)kLvl[4])  * 0.5,
    ((double)kLvl[4]  + (double)kLvl[5])  * 0.5, ((double)kLvl[5]  + (double)kLvl[6])  * 0.5,
    ((double)kLvl[6]  + (double)kLvl[7])  * 0.5, ((double)kLvl[7]  + (double)kLvl[8])  * 0.5,
    ((double)kLvl[8]  + (double)kLvl[9])  * 0.5, ((double)kLvl[9]  + (double)kLvl[10]) * 0.5,
    ((double)kLvl[10] + (double)kLvl[11]) * 0.5, ((double)kLvl[11] + (double)kLvl[12]) * 0.5,
    ((double)kLvl[12] + (double)kLvl[13]) * 0.5, ((double)kLvl[13] + (double)kLvl[14]) * 0.5,
    ((double)kLvl[14] + (double)kLvl[15]) * 0.5,
};

__device__ __forceinline__ float tree64(float v) {
    #pragma unroll
    for (int m = 1; m <= 32; m <<= 1)
        v += __shfl_xor(v, m, 64);
    return v;
}

__device__ __forceinline__ float sgpr_bcast(float x) {
    return __uint_as_float(__builtin_amdgcn_readfirstlane(__float_as_uint(x)));
}

// named-scalar select chain (verified round 7) — generic fallback only
#define QSEL(V, RES) do {                                   \
    float _u  = (V) - mean;                                 \
    float _au = fabsf(_u);                                  \
    float _o  = c0;                                         \
    _o = (_au < t0)  ? _o : c1;                             \
    _o = (_au < t1)  ? _o : c2;                             \
    _o = (_au < t2)  ? _o : c3;                             \
    _o = (_au < t3)  ? _o : c4;                             \
    _o = (_au < t4)  ? _o : c5;                             \
    _o = (_au < t5)  ? _o : c6;                             \
    _o = (_au < t6)  ? _o : c7;                             \
    _o = (_au < t7)  ? _o : c8;                             \
    _o = (_au < t8)  ? _o : c9;                             \
    _o = (_au < t9)  ? _o : c10;                            \
    _o = (_au < t10) ? _o : c11;                            \
    _o = (_au < t11) ? _o : c12;                            \
    _o = (_au < t12) ? _o : c13;                            \
    _o = (_au < t13) ? _o : c14;                            \
    _o = (_au < t14) ? _o : c15;                            \
    RES = copysignf(_o, _u);                                \
} while (0)

// bucketed table lookup (verified round 15): ~9 VALU + 1 DS per element.
#define QTAB(V, RES) do {                                            \
    float _u  = (V) - mean;                                          \
    float _au = __uint_as_float(__float_as_uint(_u) & 0x7fffffffu);  \
    unsigned _i = (unsigned)(_au * invH);                            \
    _i = _i > 127u ? 127u : _i;                                      \
    f4v _e = *(const f4v*)&tbl[_i][0];                               \
    float _o = (_au < _e.x) ? _e.y : _e.z;                           \
    RES = copysignf(_o, _u);                                         \
} while (0)

// SGPR hoist (fallback path only)
#define HOIST_TC()                                                        \
    const float t0  = sgpr_bcast(sT[0]),  t1  = sgpr_bcast(sT[1]);        \
    const float t2  = sgpr_bcast(sT[2]),  t3  = sgpr_bcast(sT[3]);        \
    const float t4  = sgpr_bcast(sT[4]),  t5  = sgpr_bcast(sT[5]);        \
    const float t6  = sgpr_bcast(sT[6]),  t7  = sgpr_bcast(sT[7]);        \
    const float t8  = sgpr_bcast(sT[8]),  t9  = sgpr_bcast(sT[9]);        \
    const float t10 = sgpr_bcast(sT[10]), t11 = sgpr_bcast(sT[11]);       \
    const float t12 = sgpr_bcast(sT[12]), t13 = sgpr_bcast(sT[13]);       \
    const float t14 = sgpr_bcast(sT[14]);                                 \
    const float c0  = sgpr_bcast(sC[0]),  c1  = sgpr_bcast(sC[1]);        \
    const float c2  = sgpr_bcast(sC[2]),  c3  = sgpr_bcast(sC[3]);        \
    const float c4  = sgpr_bcast(sC[4]),  c5  = sgpr_bcast(sC[5]);        \
    const float c6  = sgpr_bcast(sC[6]),  c7  = sgpr_bcast(sC[7]);        \
    const float c8  = sgpr_bcast(sC[8]),  c9  = sgpr_bcast(sC[9]);        \
    const float c10 = sgpr_bcast(sC[10]), c11 = sgpr_bcast(sC[11]);       \
    const float c12 = sgpr_bcast(sC[12]), c13 = sgpr_bcast(sC[13]);       \
    const float c14 = sgpr_bcast(sC[14]), c15 = sgpr_bcast(sC[15]);

// threshold binary search (verified): smallest f32 u>=0 whose IEEE f32 chain
// value u/sd -> /alpha -> clip exceeds kMid[i]
#define THRESH_SETUP(TID)                                                 \
    if ((TID) < 15) {                                                     \
        const double mid = kMid[(TID)];                                   \
        unsigned lo = 0u, hi = 0x7F800000u;                               \
        while (lo < hi) {                                                 \
            unsigned m = (lo + hi) >> 1;                                  \
            float uu = __uint_as_float(m);                                \
            float y  = uu / sd;                                           \
            float x  = y / al;                                            \
            float xc = fminf(x, 1.0f);                                    \
            if ((double)xc > mid) hi = m; else lo = m + 1;                \
        }                                                                 \
        sT[(TID)] = __uint_as_float(lo);                                  \
    } else if ((TID) < 31) {                                              \
        sC[(TID) - 15] = kLvl[(TID) - 15] * al;                           \
    } else if ((TID) == 31) {                                             \
        sC[0] = 0.0f;                                                     \
    }

// 8/thread exact complete-tree reduce over nb=2048 partials (verified r7-15)
#define GLOBAL_TREE(PART, OUT) do {                                              \
    int _i0 = threadIdx.x * 8;                                                   \
    float _v = 0.0f;                                                             \
    if (_i0 + 7 < nb) {                                                          \
        float _p0 = __hip_atomic_load(&(PART)[_i0+0], __ATOMIC_RELAXED, __HIP_MEMORY_SCOPE_AGENT); \
        float _p1 = __hip_atomic_load(&(PART)[_i0+1], __ATOMIC_RELAXED, __HIP_MEMORY_SCOPE_AGENT); \
        float _p2 = __hip_atomic_load(&(PART)[_i0+2], __ATOMIC_RELAXED, __HIP_MEMORY_SCOPE_AGENT); \
        float _p3 = __hip_atomic_load(&(PART)[_i0+3], __ATOMIC_RELAXED, __HIP_MEMORY_SCOPE_AGENT); \
        float _p4 = __hip_atomic_load(&(PART)[_i0+4], __ATOMIC_RELAXED, __HIP_MEMORY_SCOPE_AGENT); \
        float _p5 = __hip_atomic_load(&(PART)[_i0+5], __ATOMIC_RELAXED, __HIP_MEMORY_SCOPE_AGENT); \
        float _p6 = __hip_atomic_load(&(PART)[_i0+6], __ATOMIC_RELAXED, __HIP_MEMORY_SCOPE_AGENT); \
        float _p7 = __hip_atomic_load(&(PART)[_i0+7], __ATOMIC_RELAXED, __HIP_MEMORY_SCOPE_AGENT); \
        _v = ((_p0 + _p1) + (_p2 + _p3)) + ((_p4 + _p5) + (_p6 + _p7));          \
    }                                                                            \
    _v = tree64(_v);                                                             \
    if ((threadIdx.x & 63) == 0) ws4[threadIdx.x >> 6] = _v;                     \
    __syncthreads();                                                             \
    OUT = (ws4[0] + ws4[1]) + (ws4[2] + ws4[3]);                                 \
} while (0)

// verified f2v leaf body (rounds 4-15, ~6.1 TB/s = read roofline):
// 4 lanes per 128-elem numpy leaf; xor butterfly == numpy pairwise tree.
template<int SQ>
__device__ __forceinline__ float leaf_body(const float* __restrict__ w,
                                           long long region, float mean) {
    #pragma clang fp contract(off)
    const long long base = region * 8192
                         + (long long)(threadIdx.x >> 2) * 128
                         + (long long)(threadIdx.x & 3) * 2;
    const f2v* p = (const f2v*)(w + base);
    float s0, s1;
    {
        f2v a = p[0];
        if (SQ) { float x = a.x - mean, y = a.y - mean; s0 = x * x; s1 = y * y; }
        else    { s0 = a.x; s1 = a.y; }
    }
    #pragma unroll
    for (int t = 1; t < 16; ++t) {
        f2v a = p[4 * t];
        if (SQ) { float x = a.x - mean, y = a.y - mean; s0 += x * x; s1 += y * y; }
        else    { s0 += a.x; s1 += a.y; }
    }
    return tree64(s0 + s1);
}

// ---- pass 0 + last-block mean finalize (fetch_add protocol, verified r12/13;
// NO spin — last arriver does the reduce, everyone else exits).
__global__ __launch_bounds__(THREADS) void leaf0F(const float* __restrict__ w,
                                                  float* __restrict__ bout,
                                                  float* __restrict__ params,
                                                  int* __restrict__ cnt,
                                                  long long n, int nb) {
    #pragma clang fp contract(off)
    __shared__ float ws4[4];
    __shared__ int sLast;
    float s = leaf_body<0>(w, blockIdx.x, 0.0f);
    if ((threadIdx.x & 63) == 0) ws4[threadIdx.x >> 6] = s;
    __syncthreads();
    if (threadIdx.x == 0) {
        float p = (ws4[0] + ws4[1]) + (ws4[2] + ws4[3]);
        __hip_atomic_store(&bout[blockIdx.x], p, __ATOMIC_RELAXED, __HIP_MEMORY_SCOPE_AGENT);
        int prev = __hip_atomic_fetch_add(&cnt[0], 1, __ATOMIC_ACQ_REL, __HIP_MEMORY_SCOPE_AGENT);
        sLast = (prev == nb - 1);
    }
    __syncthreads();
    if (sLast) {
        float total;
        GLOBAL_TREE(bout, total);
        if (threadIdx.x == 0) params[0] = total / (float)n;   // numpy f32 mean
    }
}

// ---- pass 1 (REV region map, verified r12) + last-block sd/threshold finalize.
__global__ __launch_bounds__(THREADS) void leaf1F(const float* __restrict__ w,
                                                  float* __restrict__ bout,
                                                  float* __restrict__ params,
                                                  int* __restrict__ cnt,
                                                  const float* __restrict__ alpha_ptr,
                                                  long long n, int nb) {
    #pragma clang fp contract(off)
    __shared__ float ws4[4];
    __shared__ int sLast;
    __shared__ float sSd;
    __shared__ float sT[15], sC[16];
    const float mean = params[0];                 // coherent across dispatch boundary
    int region = blockIdx.x;
    if ((nb & 7) == 0) {                          // XCD-matched reverse map
        int j = blockIdx.x >> 3;
        region = (blockIdx.x & 7) + 8 * ((nb >> 3) - 1 - j);
    }
    float s = leaf_body<1>(w, region, mean);
    if ((threadIdx.x & 63) == 0) ws4[threadIdx.x >> 6] = s;
    __syncthreads();
    if (threadIdx.x == 0) {
        float p = (ws4[0] + ws4[1]) + (ws4[2] + ws4[3]);
        __hip_atomic_store(&bout[region], p, __ATOMIC_RELAXED, __HIP_MEMORY_SCOPE_AGENT);
        int prev = __hip_atomic_fetch_add(&cnt[0], 1, __ATOMIC_ACQ_REL, __HIP_MEMORY_SCOPE_AGENT);
        sLast = (prev == nb - 1);
    }
    __syncthreads();
    if (sLast) {
        float total;
        GLOBAL_TREE(bout, total);
        if (threadIdx.x == 0)
            sSd = sqrtf(total / (float)(n - 1));  // f32 IEEE div + sqrt, ddof=1
        __syncthreads();
        const float sd = sSd;
        const float al = alpha_ptr[0];
        THRESH_SETUP(threadIdx.x)
        __syncthreads();
        if (threadIdx.x < 15)       params[1 + threadIdx.x]  = sT[threadIdx.x];
        else if (threadIdx.x < 32)  params[threadIdx.x]      = sC[threadIdx.x - 16];
    }
}

// ---- quantize: cheap prologue (32 params) + bucket table + blocked layout +
// MLP=8 + NT stores (stream body verified r15).
__global__ __launch_bounds__(THREADS) void quantize_bp(const f4v* __restrict__ w4,
                                                       f4v* __restrict__ o4,
                                                       const float* __restrict__ params) {
    #pragma clang fp contract(off)
    __shared__ float sp[32];
    __shared__ float tbl[128][4];     // (Tq, C_lo, C_hi, pad) per bucket
    if (threadIdx.x < 32) sp[threadIdx.x] = params[threadIdx.x];
    __syncthreads();
    const float invH = sgpr_bcast(120.0f / sp[15]);   // sp[15] = T14
    if (threadIdx.x < 128) {
        const int b = threadIdx.x;
        int base = 0;
        float Tq = __builtin_inff();
        #pragma unroll
        for (int k = 0; k < 15; ++k) {
            float Tk = sp[1 + k];
            unsigned bk = (unsigned)(Tk * invH);      // same f32 mul + trunc as QTAB
            bk = bk > 127u ? 127u : bk;
            if (bk < (unsigned)b) base++;
            if (bk == (unsigned)b) Tq = Tk;
        }
        int hi = base + 1 <= 15 ? base + 1 : 15;
        tbl[b][0] = Tq;
        tbl[b][1] = sp[16 + base];
        tbl[b][2] = sp[16 + hi];
        tbl[b][3] = 0.0f;
    }
    __syncthreads();
    const float mean = sgpr_bcast(sp[0]);

    const long long base = (long long)blockIdx.x * 2048 + threadIdx.x;
    f4v a0 = w4[base];                  // 8 loads in flight (MLP=8)
    f4v a1 = w4[base + 256];
    f4v a2 = w4[base + 512];
    f4v a3 = w4[base + 768];
    f4v a4 = w4[base + 1024];
    f4v a5 = w4[base + 1280];
    f4v a6 = w4[base + 1536];
    f4v a7 = w4[base + 1792];
    f4v r;
    QTAB(a0.x, r.x); QTAB(a0.y, r.y); QTAB(a0.z, r.z); QTAB(a0.w, r.w);
    __builtin_nontemporal_store(r, &o4[base]);
    QTAB(a1.x, r.x); QTAB(a1.y, r.y); QTAB(a1.z, r.z); QTAB(a1.w, r.w);
    __builtin_nontemporal_store(r, &o4[base + 256]);
    QTAB(a2.x, r.x); QTAB(a2.y, r.y); QTAB(a2.z, r.z); QTAB(a2.w, r.w);
    __builtin_nontemporal_store(r, &o4[base + 512]);
    QTAB(a3.x, r.x); QTAB(a3.y, r.y); QTAB(a3.z, r.z); QTAB(a3.w, r.w);
    __builtin_nontemporal_store(r, &o4[base + 768]);
    QTAB(a4.x, r.x); QTAB(a4.y, r.y); QTAB(a4.z, r.z); QTAB(a4.w, r.w);
    __builtin_nontemporal_store(r, &o4[base + 1024]);
    QTAB(a5.x, r.x); QTAB(a5.y, r.y); QTAB(a5.z, r.z); QTAB(a5.w, r.w);
    __builtin_nontemporal_store(r, &o4[base + 1280]);
    QTAB(a6.x, r.x); QTAB(a6.y, r.y); QTAB(a6.z, r.z); QTAB(a6.w, r.w);
    __builtin_nontemporal_store(r, &o4[base + 1536]);
    QTAB(a7.x, r.x); QTAB(a7.y, r.y); QTAB(a7.z, r.z); QTAB(a7.w, r.w);
    __builtin_nontemporal_store(r, &o4[base + 1792]);
}

// =====================================================================
// Fallback path for n != 2^24 (round-12 verified: f2v leaves + QSEL)
// =====================================================================
template<int PASS>
__global__ __launch_bounds__(THREADS) void leaf_pass(const float* __restrict__ w,
                                                     const float* __restrict__ bprev,
                                                     float* __restrict__ bout,
                                                     long long n, int nb) {
    #pragma clang fp contract(off)
    __shared__ float ws4[4];
    __shared__ float smean;
    float mean = 0.0f;
    if (PASS == 1) {
        int i0 = threadIdx.x * 8;
        float v = 0.0f;
        if (i0 + 7 < nb) {
            const float* p = bprev + i0;
            v = ((p[0] + p[1]) + (p[2] + p[3])) + ((p[4] + p[5]) + (p[6] + p[7]));
        }
        v = tree64(v);
        if ((threadIdx.x & 63) == 0) ws4[threadIdx.x >> 6] = v;
        __syncthreads();
        if (threadIdx.x == 0)
            smean = ((ws4[0] + ws4[1]) + (ws4[2] + ws4[3])) / (float)n;
        __syncthreads();
        mean = smean;
        __syncthreads();
    }
    float s = leaf_body<PASS>(w, blockIdx.x, mean);
    if ((threadIdx.x & 63) == 0) ws4[threadIdx.x >> 6] = s;
    __syncthreads();
    if (threadIdx.x == 0)
        bout[blockIdx.x] = (ws4[0] + ws4[1]) + (ws4[2] + ws4[3]);
}

__global__ __launch_bounds__(THREADS) void quantize_g(const f4v* __restrict__ w4,
                                                      f4v* __restrict__ o4,
                                                      const float* __restrict__ bout0,
                                                      const float* __restrict__ bout1,
                                                      const float* __restrict__ alpha_ptr,
                                                      long long n, int nb) {
    #pragma clang fp contract(off)
    __shared__ float wsA[4], wsB[4];
    __shared__ float sP[2];
    __shared__ float sT[15];
    __shared__ float sC[16];
    {
        int i0 = threadIdx.x * 8;
        float v = 0.0f, u = 0.0f;
        if (i0 + 7 < nb) {
            const float* p0 = bout0 + i0;
            const float* p1 = bout1 + i0;
            v = ((p0[0] + p0[1]) + (p0[2] + p0[3])) + ((p0[4] + p0[5]) + (p0[6] + p0[7]));
            u = ((p1[0] + p1[1]) + (p1[2] + p1[3])) + ((p1[4] + p1[5]) + (p1[6] + p1[7]));
        }
        v = tree64(v);
        u = tree64(u);
        if ((threadIdx.x & 63) == 0) { wsA[threadIdx.x >> 6] = v; wsB[threadIdx.x >> 6] = u; }
        __syncthreads();
        if (threadIdx.x == 0) {
            sP[0] = ((wsA[0] + wsA[1]) + (wsA[2] + wsA[3])) / (float)n;
            sP[1] = sqrtf(((wsB[0] + wsB[1]) + (wsB[2] + wsB[3])) / (float)(n - 1));
        }
        __syncthreads();
    }
    {
        const float sd = sP[1];
        const float al = alpha_ptr[0];
        THRESH_SETUP(threadIdx.x)
    }
    __syncthreads();

    const float mean = sgpr_bcast(sP[0]);
    HOIST_TC()

    long long n4     = n >> 2;
    long long tid    = (long long)blockIdx.x * THREADS + threadIdx.x;
    long long stride = (long long)gridDim.x * THREADS;
    long long i = tid;
    for (; i + stride < n4; i += 2 * stride) {
        f4v a = w4[i];
        f4v b = w4[i + stride];
        f4v ra, rb;
        QSEL(a.x, ra.x); QSEL(a.y, ra.y); QSEL(a.z, ra.z); QSEL(a.w, ra.w);
        QSEL(b.x, rb.x); QSEL(b.y, rb.y); QSEL(b.z, rb.z); QSEL(b.w, rb.w);
        __builtin_nontemporal_store(ra, &o4[i]);
        __builtin_nontemporal_store(rb, &o4[i + stride]);
    }
    for (; i < n4; i += stride) {
        f4v a = w4[i];
        f4v ra;
        QSEL(a.x, ra.x); QSEL(a.y, ra.y); QSEL(a.z, ra.z); QSEL(a.w, ra.w);
        __builtin_nontemporal_store(ra, &o4[i]);
    }
}

extern "C" void kernel_launch(void* const* d_in, const int* in_sizes, int n_in,
                              void* d_out, int out_size, void* d_ws, size_t ws_size,
                              hipStream_t stream) {
    const float* w     = (const float*)d_in[0];
    const float* alpha = (const float*)d_in[1];
    float* out = (float*)d_out;
    long long n = (long long)in_sizes[0];          // 16777216 = 2^24

    int nblk = (int)(n >> 13);                     // 8192-elem regions -> 2048
    size_t need = 2 * sizeof(int) + (size_t)(2 * nblk + 32) * sizeof(float);
    if (n == (1LL << 24) && ws_size >= need) {
        int*   cnt    = (int*)d_ws;                // [cnt_leaf0, cnt_leaf1]
        float* bout0  = (float*)d_ws + 2;          // 2048 partials (sum)
        float* bout1  = bout0 + nblk;              // 2048 partials (sumsq)
        float* params = bout1 + nblk;              // 32: [mean, T0..14, C0..15]
        hipMemsetAsync(cnt, 0, 2 * sizeof(int), stream);
        leaf0F<<<nblk, THREADS, 0, stream>>>(w, bout0, params, cnt, n, nblk);
        leaf1F<<<nblk, THREADS, 0, stream>>>(w, bout1, params, cnt + 1, alpha, n, nblk);
        quantize_bp<<<nblk, THREADS, 0, stream>>>((const f4v*)w, (f4v*)out, params);
    } else {
        float* bout0 = (float*)d_ws;
        float* bout1 = bout0 + nblk;
        leaf_pass<0><<<nblk, THREADS, 0, stream>>>(w, nullptr, bout0, n, nblk);
        leaf_pass<1><<<nblk, THREADS, 0, stream>>>(w, bout0, bout1, n, nblk);
        quantize_g<<<2048, THREADS, 0, stream>>>((const f4v*)w, (f4v*)out,
                                                 bout0, bout1, alpha, n, nblk);
    }
}

// Round 18
// 46.191 us; speedup vs baseline: 3.6471x; 3.6471x over previous
//
#include <hip/hip_runtime.h>
#include <math.h>

#define THREADS 256

typedef float f2v __attribute__((ext_vector_type(2)));
typedef float f4v __attribute__((ext_vector_type(4)));

// ---- codebook: fp32 levels exactly as numpy float32 computes them ----
static constexpr float kLvl[16] = {
    0.0f      / 0.75f, 0.015625f / 0.75f, 0.03125f / 0.75f, 0.046875f / 0.75f,
    0.0625f   / 0.75f, 0.09375f  / 0.75f, 0.125f   / 0.75f, 0.140625f / 0.75f,
    0.1875f   / 0.75f, 0.25f     / 0.75f, 0.28125f / 0.75f, 0.375f    / 0.75f,
    0.5f      / 0.75f, 0.515625f / 0.75f, 0.5625f  / 0.75f, 0.75f     / 0.75f,
};
// exact f64 midpoints of adjacent f32 levels: strict a>mid == numpy f32 argmin (Sterbenz)
static constexpr double kMid[15] = {
    ((double)kLvl[0]  + (double)kLvl[1])  * 0.5, ((double)kLvl[1]  + (double)kLvl[2])  * 0.5,
    ((double)kLvl[2]  + (double)kLvl[3])  * 0.5, ((double)kLvl[3]  + (double)kLvl[4])  * 0.5,
    ((double)kLvl[4]  + (double)kLvl[5])  * 0.5, ((double)kLvl[5]  + (double)kLvl[6])  * 0.5,
    ((double)kLvl[6]  + (double)kLvl[7])  * 0.5, ((double)kLvl[7]  + (double)kLvl[8])  * 0.5,
    ((double)kLvl[8]  + (double)kLvl[9])  * 0.5, ((double)kLvl[9]  + (double)kLvl[10]) * 0.5,
    ((double)kLvl[10] + (double)kLvl[11]) * 0.5, ((double)kLvl[11] + (double)kLvl[12]) * 0.5,
    ((double)kLvl[12] + (double)kLvl[13]) * 0.5, ((double)kLvl[13] + (double)kLvl[14]) * 0.5,
    ((double)kLvl[14] + (double)kLvl[15]) * 0.5,
};

__device__ __forceinline__ float tree64(float v) {
    #pragma unroll
    for (int m = 1; m <= 32; m <<= 1)
        v += __shfl_xor(v, m, 64);
    return v;
}

__device__ __forceinline__ float sgpr_bcast(float x) {
    return __uint_as_float(__builtin_amdgcn_readfirstlane(__float_as_uint(x)));
}

// named-scalar select chain (verified round 7) — used by the generic fallback
#define QSEL(V, RES) do {                                   \
    float _u  = (V) - mean;                                 \
    float _au = fabsf(_u);                                  \
    float _o  = c0;                                         \
    _o = (_au < t0)  ? _o : c1;                             \
    _o = (_au < t1)  ? _o : c2;                             \
    _o = (_au < t2)  ? _o : c3;                             \
    _o = (_au < t3)  ? _o : c4;                             \
    _o = (_au < t4)  ? _o : c5;                             \
    _o = (_au < t5)  ? _o : c6;                             \
    _o = (_au < t6)  ? _o : c7;                             \
    _o = (_au < t7)  ? _o : c8;                             \
    _o = (_au < t8)  ? _o : c9;                             \
    _o = (_au < t9)  ? _o : c10;                            \
    _o = (_au < t10) ? _o : c11;                            \
    _o = (_au < t11) ? _o : c12;                            \
    _o = (_au < t12) ? _o : c13;                            \
    _o = (_au < t13) ? _o : c14;                            \
    _o = (_au < t14) ? _o : c15;                            \
    RES = copysignf(_o, _u);                                \
} while (0)

// bucketed table lookup (verified round 15): sub, abs, mul, cvt, clamp,
// ds_read_b128, cmp, cndmask, bfi — ~9 VALU + 1 DS per element.
// Correctness: bucket(x) = min(127, trunc_u32(x*invH)) is monotone non-decr;
// table entry b holds the ONE threshold with bucket==b (gap >= 2.8 buckets),
// base_b = #{k: bucket(T[k]) < b}. For au with bucket(au)=b:
//   T with bucket<b  => T <= au  (monotonicity)   -> counted in base
//   T with bucket>b  => T >  au  (monotonicity)   -> not counted
//   T with bucket==b => explicit exact compare au >= Tq
// so C_lo/C_hi = C[base]/C[base+1] selected by (au < Tq) == exact argmin.
#define QTAB(V, RES) do {                                            \
    float _u  = (V) - mean;                                          \
    float _au = __uint_as_float(__float_as_uint(_u) & 0x7fffffffu);  \
    unsigned _i = (unsigned)(_au * invH);                            \
    _i = _i > 127u ? 127u : _i;                                      \
    f4v _e = *(const f4v*)&tbl[_i][0];                               \
    float _o = (_au < _e.x) ? _e.y : _e.z;                           \
    RES = copysignf(_o, _u);                                         \
} while (0)

// SGPR hoist from sT/sC LDS arrays (verified round 7) — fallback path only
#define HOIST_TC()                                                        \
    const float t0  = sgpr_bcast(sT[0]),  t1  = sgpr_bcast(sT[1]);        \
    const float t2  = sgpr_bcast(sT[2]),  t3  = sgpr_bcast(sT[3]);        \
    const float t4  = sgpr_bcast(sT[4]),  t5  = sgpr_bcast(sT[5]);        \
    const float t6  = sgpr_bcast(sT[6]),  t7  = sgpr_bcast(sT[7]);        \
    const float t8  = sgpr_bcast(sT[8]),  t9  = sgpr_bcast(sT[9]);        \
    const float t10 = sgpr_bcast(sT[10]), t11 = sgpr_bcast(sT[11]);       \
    const float t12 = sgpr_bcast(sT[12]), t13 = sgpr_bcast(sT[13]);       \
    const float t14 = sgpr_bcast(sT[14]);                                 \
    const float c0  = sgpr_bcast(sC[0]),  c1  = sgpr_bcast(sC[1]);        \
    const float c2  = sgpr_bcast(sC[2]),  c3  = sgpr_bcast(sC[3]);        \
    const float c4  = sgpr_bcast(sC[4]),  c5  = sgpr_bcast(sC[5]);        \
    const float c6  = sgpr_bcast(sC[6]),  c7  = sgpr_bcast(sC[7]);        \
    const float c8  = sgpr_bcast(sC[8]),  c9  = sgpr_bcast(sC[9]);        \
    const float c10 = sgpr_bcast(sC[10]), c11 = sgpr_bcast(sC[11]);       \
    const float c12 = sgpr_bcast(sC[12]), c13 = sgpr_bcast(sC[13]);       \
    const float c14 = sgpr_bcast(sC[14]), c15 = sgpr_bcast(sC[15]);

// threshold binary search (verified): smallest f32 u>=0 whose IEEE f32 chain
// value u/sd -> /alpha -> clip exceeds kMid[i]
#define THRESH_SETUP(TID)                                                 \
    if ((TID) < 15) {                                                     \
        const double mid = kMid[(TID)];                                   \
        unsigned lo = 0u, hi = 0x7F800000u;                               \
        while (lo < hi) {                                                 \
            unsigned m = (lo + hi) >> 1;                                  \
            float uu = __uint_as_float(m);                                \
            float y  = uu / sd;                                           \
            float x  = y / al;                                            \
            float xc = fminf(x, 1.0f);                                    \
            if ((double)xc > mid) hi = m; else lo = m + 1;                \
        }                                                                 \
        sT[(TID)] = __uint_as_float(lo);                                  \
    } else if ((TID) < 31) {                                              \
        sC[(TID) - 15] = kLvl[(TID) - 15] * al;                           \
    } else if ((TID) == 31) {                                             \
        sC[0] = 0.0f;                                                     \
    }

// ---- leaf pass (verified rounds 4-15 — ~6.1 TB/s, at read roofline).
// 4 lanes per 128-elem numpy leaf; xor butterfly == numpy pairwise tree.
// Block = 64 leaves = 8192 elems. REV=1: XCD-matched reverse region map.
template<int PASS, int REV>
__global__ __launch_bounds__(THREADS) void leaf_pass(const float* __restrict__ w,
                                                     const float* __restrict__ bprev,
                                                     float* __restrict__ bout,
                                                     long long n, int nb) {
    #pragma clang fp contract(off)
    __shared__ float ws4[4];
    __shared__ float smean;
    float mean = 0.0f;
    if (PASS == 1) {
        int i0 = threadIdx.x * 8;
        float v = 0.0f;
        if (i0 + 7 < nb) {
            const float* p = bprev + i0;
            v = ((p[0] + p[1]) + (p[2] + p[3])) + ((p[4] + p[5]) + (p[6] + p[7]));
        }
        v = tree64(v);
        if ((threadIdx.x & 63) == 0) ws4[threadIdx.x >> 6] = v;
        __syncthreads();
        if (threadIdx.x == 0)
            smean = ((ws4[0] + ws4[1]) + (ws4[2] + ws4[3])) / (float)n;
        __syncthreads();
        mean = smean;
    }
    int region = blockIdx.x;
    if (REV && (nb & 7) == 0) {
        int j = blockIdx.x >> 3;
        region = (blockIdx.x & 7) + 8 * ((nb >> 3) - 1 - j);
    }
    const long long base = (long long)region * 8192
                         + (long long)(threadIdx.x >> 2) * 128
                         + (long long)(threadIdx.x & 3) * 2;
    const f2v* p = (const f2v*)(w + base);
    float s0, s1;
    {
        f2v a = p[0];
        if (PASS == 1) { float x = a.x - mean, y = a.y - mean; s0 = x * x; s1 = y * y; }
        else           { s0 = a.x; s1 = a.y; }
    }
    #pragma unroll
    for (int t = 1; t < 16; ++t) {
        f2v a = p[4 * t];
        if (PASS == 1) { float x = a.x - mean, y = a.y - mean; s0 += x * x; s1 += y * y; }
        else           { s0 += a.x; s1 += a.y; }
    }
    float s = s0 + s1;
    s = tree64(s);
    if ((threadIdx.x & 63) == 0) ws4[threadIdx.x >> 6] = s;
    __syncthreads();
    if (threadIdx.x == 0)
        bout[region] = (ws4[0] + ws4[1]) + (ws4[2] + ws4[3]);
}

// ---- fused quantize (fast path, n = 2^24, nb = 2048): finalize prologue +
// blocked identity layout + MLP=8 + NT stores + QTAB bucket table (all
// verified rounds 12/15 — champion configuration, 46.29 us).
__global__ __launch_bounds__(THREADS) void quantize_b(const f4v* __restrict__ w4,
                                                      f4v* __restrict__ o4,
                                                      const float* __restrict__ bout0,
                                                      const float* __restrict__ bout1,
                                                      const float* __restrict__ alpha_ptr,
                                                      long long n, int nb) {
    #pragma clang fp contract(off)
    __shared__ float wsA[4], wsB[4];
    __shared__ float sP[2];
    __shared__ float sT[15];
    __shared__ float sC[16];
    __shared__ float sInvH;
    __shared__ float tbl[128][4];     // (Tq, C_lo, C_hi, pad) per bucket
    {
        int i0 = threadIdx.x * 8;
        float v = 0.0f, u = 0.0f;
        if (i0 + 7 < nb) {
            const float* p0 = bout0 + i0;
            const float* p1 = bout1 + i0;
            v = ((p0[0] + p0[1]) + (p0[2] + p0[3])) + ((p0[4] + p0[5]) + (p0[6] + p0[7]));
            u = ((p1[0] + p1[1]) + (p1[2] + p1[3])) + ((p1[4] + p1[5]) + (p1[6] + p1[7]));
        }
        v = tree64(v);
        u = tree64(u);
        if ((threadIdx.x & 63) == 0) { wsA[threadIdx.x >> 6] = v; wsB[threadIdx.x >> 6] = u; }
        __syncthreads();
        if (threadIdx.x == 0) {
            sP[0] = ((wsA[0] + wsA[1]) + (wsA[2] + wsA[3])) / (float)n;
            sP[1] = sqrtf(((wsB[0] + wsB[1]) + (wsB[2] + wsB[3])) / (float)(n - 1));
        }
        __syncthreads();
    }
    {
        const float sd = sP[1];
        const float al = alpha_ptr[0];
        THRESH_SETUP(threadIdx.x)
    }
    __syncthreads();
    if (threadIdx.x == 0) sInvH = 120.0f / sT[14];   // bucket(T14) ~ 120 < 127
    __syncthreads();
    const float invH = sgpr_bcast(sInvH);
    // build bucket table: thread b in [0,128)
    if (threadIdx.x < 128) {
        const int b = threadIdx.x;
        int base = 0;
        float Tq = __builtin_inff();
        #pragma unroll
        for (int k = 0; k < 15; ++k) {
            float Tk = sT[k];
            unsigned bk = (unsigned)(Tk * invH);     // same f32 mul + trunc as QTAB
            bk = bk > 127u ? 127u : bk;
            if (bk < (unsigned)b) base++;
            if (bk == (unsigned)b) Tq = Tk;
        }
        int hi = base + 1 <= 15 ? base + 1 : 15;
        tbl[b][0] = Tq;
        tbl[b][1] = sC[base];
        tbl[b][2] = sC[hi];
        tbl[b][3] = 0.0f;
    }
    __syncthreads();

    const float mean = sgpr_bcast(sP[0]);

    // block b covers f4v [b*2048, (b+1)*2048); thread t: base + k*256, k=0..7
    const long long base = (long long)blockIdx.x * 2048 + threadIdx.x;
    f4v a0 = w4[base];                  // 8 loads issued up front (MLP=8)
    f4v a1 = w4[base + 256];
    f4v a2 = w4[base + 512];
    f4v a3 = w4[base + 768];
    f4v a4 = w4[base + 1024];
    f4v a5 = w4[base + 1280];
    f4v a6 = w4[base + 1536];
    f4v a7 = w4[base + 1792];
    f4v r;
    QTAB(a0.x, r.x); QTAB(a0.y, r.y); QTAB(a0.z, r.z); QTAB(a0.w, r.w);
    __builtin_nontemporal_store(r, &o4[base]);
    QTAB(a1.x, r.x); QTAB(a1.y, r.y); QTAB(a1.z, r.z); QTAB(a1.w, r.w);
    __builtin_nontemporal_store(r, &o4[base + 256]);
    QTAB(a2.x, r.x); QTAB(a2.y, r.y); QTAB(a2.z, r.z); QTAB(a2.w, r.w);
    __builtin_nontemporal_store(r, &o4[base + 512]);
    QTAB(a3.x, r.x); QTAB(a3.y, r.y); QTAB(a3.z, r.z); QTAB(a3.w, r.w);
    __builtin_nontemporal_store(r, &o4[base + 768]);
    QTAB(a4.x, r.x); QTAB(a4.y, r.y); QTAB(a4.z, r.z); QTAB(a4.w, r.w);
    __builtin_nontemporal_store(r, &o4[base + 1024]);
    QTAB(a5.x, r.x); QTAB(a5.y, r.y); QTAB(a5.z, r.z); QTAB(a5.w, r.w);
    __builtin_nontemporal_store(r, &o4[base + 1280]);
    QTAB(a6.x, r.x); QTAB(a6.y, r.y); QTAB(a6.z, r.z); QTAB(a6.w, r.w);
    __builtin_nontemporal_store(r, &o4[base + 1536]);
    QTAB(a7.x, r.x); QTAB(a7.y, r.y); QTAB(a7.z, r.z); QTAB(a7.w, r.w);
    __builtin_nontemporal_store(r, &o4[base + 1792]);
}

// ---- generic-n fallback quantize (round 12, verified) ----
__global__ __launch_bounds__(THREADS) void quantize_g(const f4v* __restrict__ w4,
                                                      f4v* __restrict__ o4,
                                                      const float* __restrict__ bout0,
                                                      const float* __restrict__ bout1,
                                                      const float* __restrict__ alpha_ptr,
                                                      long long n, int nb) {
    #pragma clang fp contract(off)
    __shared__ float wsA[4], wsB[4];
    __shared__ float sP[2];
    __shared__ float sT[15];
    __shared__ float sC[16];
    {
        int i0 = threadIdx.x * 8;
        float v = 0.0f, u = 0.0f;
        if (i0 + 7 < nb) {
            const float* p0 = bout0 + i0;
            const float* p1 = bout1 + i0;
            v = ((p0[0] + p0[1]) + (p0[2] + p0[3])) + ((p0[4] + p0[5]) + (p0[6] + p0[7]));
            u = ((p1[0] + p1[1]) + (p1[2] + p1[3])) + ((p1[4] + p1[5]) + (p1[6] + p1[7]));
        }
        v = tree64(v);
        u = tree64(u);
        if ((threadIdx.x & 63) == 0) { wsA[threadIdx.x >> 6] = v; wsB[threadIdx.x >> 6] = u; }
        __syncthreads();
        if (threadIdx.x == 0) {
            sP[0] = ((wsA[0] + wsA[1]) + (wsA[2] + wsA[3])) / (float)n;
            sP[1] = sqrtf(((wsB[0] + wsB[1]) + (wsB[2] + wsB[3])) / (float)(n - 1));
        }
        __syncthreads();
    }
    {
        const float sd = sP[1];
        const float al = alpha_ptr[0];
        THRESH_SETUP(threadIdx.x)
    }
    __syncthreads();

    const float mean = sgpr_bcast(sP[0]);
    HOIST_TC()

    long long n4     = n >> 2;
    long long tid    = (long long)blockIdx.x * THREADS + threadIdx.x;
    long long stride = (long long)gridDim.x * THREADS;
    long long i = tid;
    for (; i + stride < n4; i += 2 * stride) {
        f4v a = w4[i];
        f4v b = w4[i + stride];
        f4v ra, rb;
        QSEL(a.x, ra.x); QSEL(a.y, ra.y); QSEL(a.z, ra.z); QSEL(a.w, ra.w);
        QSEL(b.x, rb.x); QSEL(b.y, rb.y); QSEL(b.z, rb.z); QSEL(b.w, rb.w);
        __builtin_nontemporal_store(ra, &o4[i]);
        __builtin_nontemporal_store(rb, &o4[i + stride]);
    }
    for (; i < n4; i += stride) {
        f4v a = w4[i];
        f4v ra;
        QSEL(a.x, ra.x); QSEL(a.y, ra.y); QSEL(a.z, ra.z); QSEL(a.w, ra.w);
        __builtin_nontemporal_store(ra, &o4[i]);
    }
}

extern "C" void kernel_launch(void* const* d_in, const int* in_sizes, int n_in,
                              void* d_out, int out_size, void* d_ws, size_t ws_size,
                              hipStream_t stream) {
    const float* w     = (const float*)d_in[0];
    const float* alpha = (const float*)d_in[1];
    float* out = (float*)d_out;
    long long n = (long long)in_sizes[0];          // 16777216 = 2^24

    int nblk = (int)(n >> 13);                     // 8192 elems/block -> 2048 blocks
    float* bout0 = (float*)d_ws;                   // nblk partials (sum)
    float* bout1 = bout0 + nblk;                   // nblk partials (sumsq)

    leaf_pass<0, 0><<<nblk, THREADS, 0, stream>>>(w, nullptr, bout0, n, nblk);
    leaf_pass<1, 1><<<nblk, THREADS, 0, stream>>>(w, bout0, bout1, n, nblk);
    if (n == (1LL << 24)) {
        quantize_b<<<nblk, THREADS, 0, stream>>>((const f4v*)w, (f4v*)out,
                                                 bout0, bout1, alpha, n, nblk);
    } else {
        quantize_g<<<2048, THREADS, 0, stream>>>((const f4v*)w, (f4v*)out,
                                                 bout0, bout1, alpha, n, nblk);
    }
}